// Round 6
// baseline (539.055 us; speedup 1.0000x reference)
//
#include <hip/hip_runtime.h>
#include <math.h>

// alpha-entmax via bisection (ref: entmax.EntmaxBisect, 50 iters).
// R10: two stream-ordered dispatches, each a pure high-TLP stream.
//
// R4-R9 lesson: effective BW tracked OCCUPANCY (66%->2.55, 36%->2.2,
// 21%->1.8 TB/s), not per-wave MLP. Any fused structure must HOLD the
// 128KB row (regs: compiler war R5/R6/R8; LDS: 1 block/CU R9) while
// serial phases idle the HBM. Fix: don't hold the row.
//   K1: per-row max/min reduce -> ws. 2048x256, ~32 VGPR, 64B LDS,
//       all 8 blocks/CU resident. Pure read stream (m13 shape).
//   K2: exact threshold known up front (no running-max machinery!):
//       stream {load x, test, append, zero-store}, lgkm-barrier,
//       redundant all-wave reg-Newton (hides under zero-store drain),
//       __syncthreads (drain), scatter p onto L2-dirty lines.
//
// Facts exploited: tau >= maxX-1 => only elements with X > maxX-1 can be
// nonzero (~200-700 of 32000); alpha=1.5 => f(tau) convex decreasing,
// monotone Newton ~8-12 iters; am1<0 handled via min (maxX = am1<0 ?
// am1*min : am1*max); candidate test done in X domain (sign-safe).

#define D_DIM   32000
#define NV4     8000

#define B1      256
#define K1CH    32            // ceil(8000/256)

#define B2      512
#define NWAVE2  8
#define K2CH    16            // ceil(8000/512)
#define CAP     4096          // typical n_act ~200-700; overflow path below
#define NCREG   16            // fast path: <=1024 candidates in regs
#define NEWTON_MAX 30
#define NITER   50

__device__ __forceinline__ float wave_sum(float v) {
#pragma unroll
    for (int off = 32; off > 0; off >>= 1) v += __shfl_xor(v, off, 64);
    return v;
}
__device__ __forceinline__ float pf(float z, bool sq, float expo) {
    z = fmaxf(z, 0.0f);
    return sq ? z * z : powf(z, expo);
}
// lgkm-only barrier: publishes LDS without draining vmcnt (keeps the
// zero-fill stores in flight under the solve).
__device__ __forceinline__ void block_sync_lds() {
    asm volatile("s_waitcnt lgkmcnt(0)" ::: "memory");
    __builtin_amdgcn_s_barrier();
    asm volatile("" ::: "memory");
}

// ---------------- K1: per-row max & min (pure read stream) ----------------
__global__ __launch_bounds__(B1, 8)
void row_minmax_kernel(const float* __restrict__ x,
                       float* __restrict__ ws_max,
                       float* __restrict__ ws_min) {
    const int row  = blockIdx.x;
    const int tid  = threadIdx.x;
    const int lane = tid & 63;
    const int wid  = tid >> 6;
    const float4* __restrict__ x4 = (const float4*)(x + (size_t)row * D_DIM);

    float mx = -INFINITY, mn = INFINITY;
#pragma unroll
    for (int k = 0; k < K1CH; ++k) {
        const int i4 = tid + (k << 8);
        if (i4 < NV4) {
            const float4 v = x4[i4];
            mx = fmaxf(mx, fmaxf(fmaxf(v.x, v.y), fmaxf(v.z, v.w)));
            mn = fminf(mn, fminf(fminf(v.x, v.y), fminf(v.z, v.w)));
        }
    }
#pragma unroll
    for (int off = 32; off > 0; off >>= 1) {
        mx = fmaxf(mx, __shfl_xor(mx, off, 64));
        mn = fminf(mn, __shfl_xor(mn, off, 64));
    }
    __shared__ float smx[B1 / 64], smn[B1 / 64];
    if (lane == 0) { smx[wid] = mx; smn[wid] = mn; }
    __syncthreads();
    if (tid == 0) {
        float a = smx[0], b = smn[0];
#pragma unroll
        for (int w = 1; w < B1 / 64; ++w) {
            a = fmaxf(a, smx[w]); b = fminf(b, smn[w]);
        }
        ws_max[row] = a; ws_min[row] = b;
    }
}

// ---------------- K2: solve + zero-fill + scatter --------------------------
__global__ __launch_bounds__(B2, 4)
void solve_apply_kernel(const float* __restrict__ x,
                        const float* __restrict__ alpha_p,
                        const float* __restrict__ ws_max,
                        const float* __restrict__ ws_min,
                        float* __restrict__ out) {
    const int row  = blockIdx.x;
    const int tid  = threadIdx.x;
    const int lane = tid & 63;

    __shared__ float          s_val[CAP];    // 16 KB, X-domain candidates
    __shared__ unsigned short s_idx[CAP];    //  8 KB
    __shared__ float          s_red[NWAVE2];
    __shared__ int            s_cnt;

    const float alpha = alpha_p[0];
    const float am1   = alpha - 1.0f;
    const float expo  = 1.0f / am1;
    const bool  sq    = (expo == 2.0f);      // alpha == 1.5 exact fast path

    // exact global max of X = x*am1 (sign-safe via min for am1<0)
    const float maxX    = (am1 >= 0.0f) ? am1 * ws_max[row] : am1 * ws_min[row];
    const float tau_lo0 = maxX - 1.0f;       // exact candidate threshold (X dom)

    const float4* __restrict__ x4 = (const float4*)(x + (size_t)row * D_DIM);
    float4*       __restrict__ o4 = (float4*)(out + (size_t)row * D_DIM);
    float*        __restrict__ orow = out + (size_t)row * D_DIM;

    if (tid == 0) s_cnt = 0;
    __syncthreads();

    // ---- stream: load -> exact-threshold test -> append -> zero-store ----
    const float4 zero4 = make_float4(0.f, 0.f, 0.f, 0.f);
    for (int k = 0; k < K2CH; ++k) {
        const int i4 = tid + (k << 9);
        float  X[4];
        bool   on[4];
        int    cnt = 0;
        if (i4 < NV4) {
            const float4 v = x4[i4];
            X[0] = v.x * am1; X[1] = v.y * am1;
            X[2] = v.z * am1; X[3] = v.w * am1;
#pragma unroll
            for (int c = 0; c < 4; ++c) {
                on[c] = X[c] > tau_lo0;
                cnt += (int)on[c];
            }
            o4[i4] = zero4;                  // fire-and-forget
        } else {
#pragma unroll
            for (int c = 0; c < 4; ++c) on[c] = false;
        }
        // wave-aggregated append (typ. 0-3 per wave per chunk)
        int inc = cnt;
#pragma unroll
        for (int off = 1; off < 64; off <<= 1) {
            const int t = __shfl_up(inc, off, 64);
            if (lane >= off) inc += t;
        }
        const int wtotal = __shfl(inc, 63, 64);
        if (wtotal > 0) {
            int base = 0;
            if (lane == 63) base = atomicAdd(&s_cnt, wtotal);
            base = __shfl(base, 63, 64);
            int pos = base + (inc - cnt);
#pragma unroll
            for (int c = 0; c < 4; ++c)
                if (on[c]) {
                    if (pos < CAP) {
                        s_val[pos] = X[c];
                        s_idx[pos] = (unsigned short)(i4 * 4 + c);
                    }
                    ++pos;
                }
        }
    }
    block_sync_lds();            // publish candidates; zero-stores stay in flight
    const int n_act = s_cnt;

    if (n_act <= CAP) {
        // ---- redundant solve on ALL waves (identical data -> identical tau)
        float tau, S;
        if (n_act <= NCREG * 64) {
            float c[NCREG];
#pragma unroll
            for (int j = 0; j < NCREG; ++j) {
                const int idx = (j << 6) + lane;
                c[j] = (idx < n_act) ? s_val[idx] : -INFINITY;   // pads: z=0
            }
            if (sq) {
                tau = tau_lo0;               // monotone Newton
                for (int it = 0; it < NEWTON_MAX; ++it) {
                    float s1 = 0.f, s2 = 0.f;
#pragma unroll
                    for (int j = 0; j < NCREG; ++j) {
                        const float z = fmaxf(c[j] - tau, 0.f);
                        s1 += z; s2 += z * z;
                    }
#pragma unroll
                    for (int off = 32; off > 0; off >>= 1) {
                        s1 += __shfl_xor(s1, off, 64);
                        s2 += __shfl_xor(s2, off, 64);
                    }
                    const float dtau = (s2 - 1.0f) / fmaxf(2.0f * s1, 1e-30f);
                    tau += dtau;
                    if (dtau < 1e-7f * fmaxf(1.0f, fabsf(tau))) break;
                }
                float s2 = 0.f;
#pragma unroll
                for (int j = 0; j < NCREG; ++j) {
                    const float z = fmaxf(c[j] - tau, 0.f);
                    s2 += z * z;
                }
                S = wave_sum(s2);
            } else {
                // generic alpha: faithful 50-step bisection over candidates
                const float tau_hi = maxX - powf(1.0f / (float)D_DIM, am1);
                float dm = tau_hi - tau_lo0;
                float s = 0.f;
#pragma unroll
                for (int j = 0; j < NCREG; ++j) s += pf(c[j] - tau_lo0, sq, expo);
                s = wave_sum(s);
                const float f_lo = s - 1.0f;
                float tlo = tau_lo0, tau_m = tau_lo0, fsum = s;
                for (int it = 0; it < NITER; ++it) {
                    dm *= 0.5f;
                    tau_m = tlo + dm;
                    float t = 0.f;
#pragma unroll
                    for (int j = 0; j < NCREG; ++j) t += pf(c[j] - tau_m, sq, expo);
                    t = wave_sum(t);
                    fsum = t;
                    if ((t - 1.0f) * f_lo >= 0.0f) tlo = tau_m;
                }
                tau = tau_m; S = fsum;
            }
        } else {
            // mid path: redundant per-wave strided LDS loops (rare)
            if (sq) {
                tau = tau_lo0;
                for (int it = 0; it < NEWTON_MAX; ++it) {
                    float s1 = 0.f, s2 = 0.f;
                    for (int i = lane; i < n_act; i += 64) {
                        const float z = fmaxf(s_val[i] - tau, 0.f);
                        s1 += z; s2 += z * z;
                    }
#pragma unroll
                    for (int off = 32; off > 0; off >>= 1) {
                        s1 += __shfl_xor(s1, off, 64);
                        s2 += __shfl_xor(s2, off, 64);
                    }
                    const float dtau = (s2 - 1.0f) / fmaxf(2.0f * s1, 1e-30f);
                    tau += dtau;
                    if (dtau < 1e-7f * fmaxf(1.0f, fabsf(tau))) break;
                }
                float s2 = 0.f;
                for (int i = lane; i < n_act; i += 64) {
                    const float z = fmaxf(s_val[i] - tau, 0.f);
                    s2 += z * z;
                }
                S = wave_sum(s2);
            } else {
                const float tau_hi = maxX - powf(1.0f / (float)D_DIM, am1);
                float dm = tau_hi - tau_lo0;
                float s = 0.f;
                for (int i = lane; i < n_act; i += 64)
                    s += pf(s_val[i] - tau_lo0, sq, expo);
                s = wave_sum(s);
                const float f_lo = s - 1.0f;
                float tlo = tau_lo0, tau_m = tau_lo0, fsum = s;
                for (int it = 0; it < NITER; ++it) {
                    dm *= 0.5f;
                    tau_m = tlo + dm;
                    float t = 0.f;
                    for (int i = lane; i < n_act; i += 64)
                        t += pf(s_val[i] - tau_m, sq, expo);
                    t = wave_sum(t);
                    fsum = t;
                    if ((t - 1.0f) * f_lo >= 0.0f) tlo = tau_m;
                }
                tau = tau_m; S = fsum;
            }
        }
        __syncthreads();         // drains zero-stores (vmcnt(0)) block-wide

        // ---- scatter nonzeros onto L2-dirty zeroed lines ----
        const float invS = 1.0f / S;
        for (int i = tid; i < n_act; i += B2) {
            const float z = fmaxf(s_val[i] - tau, 0.f);
            const float p = sq ? z * z : powf(z, expo);
            orow[s_idx[i]] = p * invS;
        }
    } else {
        // ---- overflow fallback (pathological): full-row 50-step bisection
        //      re-reading x (L2/L3-hot) each iteration.
        const float tau_hi = maxX - powf(1.0f / (float)D_DIM, am1);
        float dm = tau_hi - tau_lo0;
        float s = 0.f;
        for (int i4 = tid; i4 < NV4; i4 += B2) {
            const float4 v = x4[i4];
            s += pf(v.x * am1 - tau_lo0, sq, expo) + pf(v.y * am1 - tau_lo0, sq, expo)
               + pf(v.z * am1 - tau_lo0, sq, expo) + pf(v.w * am1 - tau_lo0, sq, expo);
        }
        s = wave_sum(s);
        const int wid = tid >> 6;
        __syncthreads();
        if (lane == 0) s_red[wid] = s;
        __syncthreads();
        float tot = 0.f;
#pragma unroll
        for (int w = 0; w < NWAVE2; ++w) tot += s_red[w];
        const float f_lo = tot - 1.0f;
        float tlo = tau_lo0, tau_m = tau_lo0, fsum = tot;
        for (int it = 0; it < NITER; ++it) {
            dm *= 0.5f;
            tau_m = tlo + dm;
            float t = 0.f;
            for (int i4 = tid; i4 < NV4; i4 += B2) {
                const float4 v = x4[i4];
                t += pf(v.x * am1 - tau_m, sq, expo) + pf(v.y * am1 - tau_m, sq, expo)
                   + pf(v.z * am1 - tau_m, sq, expo) + pf(v.w * am1 - tau_m, sq, expo);
            }
            t = wave_sum(t);
            __syncthreads();
            if (lane == 0) s_red[wid] = t;
            __syncthreads();
            float tt = 0.f;
#pragma unroll
            for (int w = 0; w < NWAVE2; ++w) tt += s_red[w];
            fsum = tt;
            if ((tt - 1.0f) * f_lo >= 0.0f) tlo = tau_m;
        }
        const float invS = 1.0f / fsum;
        __syncthreads();         // drain zero-fill stores before overwrite
        for (int i4 = tid; i4 < NV4; i4 += B2) {
            const float4 v = x4[i4];
            float4 o;
            o.x = pf(v.x * am1 - tau_m, sq, expo) * invS;
            o.y = pf(v.y * am1 - tau_m, sq, expo) * invS;
            o.z = pf(v.z * am1 - tau_m, sq, expo) * invS;
            o.w = pf(v.w * am1 - tau_m, sq, expo) * invS;
            o4[i4] = o;
        }
    }
}

extern "C" void kernel_launch(void* const* d_in, const int* in_sizes, int n_in,
                              void* d_out, int out_size, void* d_ws, size_t ws_size,
                              hipStream_t stream) {
    const float* x       = (const float*)d_in[0];
    const float* alpha_p = (const float*)d_in[1];
    float* out           = (float*)d_out;
    const int rows       = in_sizes[0] / D_DIM;      // 2048
    float* ws_max        = (float*)d_ws;
    float* ws_min        = ws_max + rows;            // 16 KB total workspace

    row_minmax_kernel<<<rows, B1, 0, stream>>>(x, ws_max, ws_min);
    solve_apply_kernel<<<rows, B2, 0, stream>>>(x, alpha_p, ws_max, ws_min, out);
}